// Round 6
// baseline (234.822 us; speedup 1.0000x reference)
//
#include <hip/hip_runtime.h>
#include <hip/hip_bf16.h>

// B=4, T=2048, C=1024, H=16, D=64. f32 in/out; bf16 MFMA internally.

typedef __attribute__((ext_vector_type(8))) short bf16x8;
typedef __attribute__((ext_vector_type(4))) float f32x4;

#define T_DIM 2048
#define NHEAD 16
#define HDIM  64

__device__ __forceinline__ unsigned short f2bf(float f) {
    union { float f; unsigned int u; } v; v.f = f;
    unsigned int r = v.u + 0x7fffu + ((v.u >> 16) & 1u);   // RNE
    return (unsigned short)(r >> 16);
}

__device__ __forceinline__ void gload_lds16(const void* g, void* l) {
    __builtin_amdgcn_global_load_lds(
        (const __attribute__((address_space(1))) void*)g,
        (__attribute__((address_space(3))) void*)l,
        16, 0, 0);
}

// ---------------- f32 -> bf16 convert (vectorized) ----------------
__global__ void cvt_bf16_k(const float* __restrict__ src, unsigned short* __restrict__ dst, int n) {
    int i = (blockIdx.x * blockDim.x + threadIdx.x) * 4;
    if (i < n) {
        float4 v = *(const float4*)(src + i);
        ushort4 o; o.x = f2bf(v.x); o.y = f2bf(v.y); o.z = f2bf(v.z); o.w = f2bf(v.w);
        *(ushort4*)(dst + i) = o;
    }
}

// ---------------- transpose f32 [R][Cc] -> bf16 [Cc][R] ----------------
__global__ void transpose_wb_k(const float* __restrict__ src, unsigned short* __restrict__ dst,
                               int R, int Cc) {
    __shared__ float tile[32][33];
    int c0 = blockIdx.x * 32, r0 = blockIdx.y * 32;
    int tx = threadIdx.x & 31, ty = threadIdx.x >> 5;   // 32 x 8
    #pragma unroll
    for (int i = 0; i < 32; i += 8)
        tile[ty + i][tx] = src[(size_t)(r0 + ty + i) * Cc + c0 + tx];
    __syncthreads();
    #pragma unroll
    for (int i = 0; i < 32; i += 8)
        dst[(size_t)(c0 + ty + i) * R + r0 + tx] = f2bf(tile[tx][ty + i]);
}

// ---------------- bf16 transpose V [bh][t][d] -> V^T [bh][d][t] ----------------
__global__ __launch_bounds__(256) void transpose_v_k(const unsigned short* __restrict__ vb,
                                                     unsigned short* __restrict__ vt) {
    __shared__ __align__(16) unsigned short L[64 * 72];
    const int bh = blockIdx.y, t0 = blockIdx.x * 64;
    const int tid = threadIdx.x;
    const unsigned short* src = vb + ((size_t)bh * T_DIM + t0) * HDIM;
    #pragma unroll
    for (int i = 0; i < 2; ++i) {
        int cc = tid + i * 256;            // 0..511
        int r = cc >> 3, g = cc & 7;
        *(uint4*)&L[r * 72 + g * 8] = *(const uint4*)(src + r * 64 + g * 8);
    }
    __syncthreads();
    unsigned short* dst = vt + (size_t)bh * HDIM * T_DIM + t0;
    #pragma unroll
    for (int i = 0; i < 2; ++i) {
        int cc = tid + i * 256;
        int d = cc >> 3, gt = cc & 7;
        unsigned short tmp[8];
        #pragma unroll
        for (int j = 0; j < 8; ++j) tmp[j] = L[(gt * 8 + j) * 72 + d];
        *(uint4*)(dst + (size_t)d * T_DIM + gt * 8) = *(uint4*)tmp;
    }
}

// ---------------- 256x128 double-buffered 2-phase GEMM, C = A[M,K] * Bt[N,K]^T ----------------
// 8 waves (4M x 2N), per-wave 64x64 out. BK=64. LDS: 2 bufs x (A 32K + B 16K) = 96 KiB.
// Per tile (T3-min recipe, m248): STAGE(next -> buf^1) first; 16 ds_read_b128; 32 MFMA
// (setprio-wrapped); one __syncthreads() (vmcnt+lgkm drain + barrier).
// Blocked LDS layout [8 kg][rows][8 elem]: conflict-free b128 reads, linear gload dest.
// EPI==0: scatter bf16 q/k/v [B,H,T,D]; q scaled by 0.125*log2(e). EPI==1: f32 [M,N].
template<int EPI>
__global__ __launch_bounds__(512, 2) void gemm_bt_k(
    const unsigned short* __restrict__ A, const unsigned short* __restrict__ Bt,
    void* __restrict__ out0, void* __restrict__ out1, void* __restrict__ out2,
    int M, int N, int K)
{
    extern __shared__ __align__(16) unsigned short smem[];
    unsigned short* sA = smem;           // [2][8][256][8] = 32768 shorts
    unsigned short* sB = smem + 32768;   // [2][8][128][8] = 16384 shorts

    const int tid = threadIdx.x, lane = tid & 63, wave = tid >> 6;
    const int wm = wave >> 1, wn = wave & 1;     // 4M x 2N
    const int lrow = lane & 15, hi = lane >> 4;

    // bijective XCD-chunked swizzle (nwg % 8 == 0 for our grids)
    const int nwg = gridDim.x * gridDim.y;
    const int lin = blockIdx.y * gridDim.x + blockIdx.x;
    const int lin2 = (lin & 7) * (nwg >> 3) + (lin >> 3);
    const int bxg = lin2 % gridDim.x, byg = lin2 / gridDim.x;
    const int row0 = byg * 256, col0 = bxg * 128;

    // staging source bases: A-tile 2048 chunks (4/thread), B-tile 1024 (2/thread);
    // chunk c = kg*ROWS + row -> LDS dest c*16B (linear, wave-uniform base + lane*16)
    const unsigned short* gA0 = A + (size_t)(row0 + (tid & 255)) * K + (tid >> 8) * 8;
    const unsigned short* gA1 = A + (size_t)(row0 + ((tid + 512) & 255)) * K + ((tid + 512) >> 8) * 8;
    const unsigned short* gA2 = A + (size_t)(row0 + ((tid + 1024) & 255)) * K + ((tid + 1024) >> 8) * 8;
    const unsigned short* gA3 = A + (size_t)(row0 + ((tid + 1536) & 255)) * K + ((tid + 1536) >> 8) * 8;
    const unsigned short* gB0 = Bt + (size_t)(col0 + (tid & 127)) * K + (tid >> 7) * 8;
    const unsigned short* gB1 = Bt + (size_t)(col0 + ((tid + 512) & 127)) * K + ((tid + 512) >> 7) * 8;

    const int NT = K >> 6;   // K-tiles of 64

#define STAGE(ts, bsel) { const size_t ko_ = (size_t)(ts) * 64; \
        unsigned short* dA_ = sA + (bsel) * 16384; \
        unsigned short* dB_ = sB + (bsel) * 8192; \
        gload_lds16(gA0 + ko_, dA_ + tid * 8); \
        gload_lds16(gA1 + ko_, dA_ + (tid + 512) * 8); \
        gload_lds16(gA2 + ko_, dA_ + (tid + 1024) * 8); \
        gload_lds16(gA3 + ko_, dA_ + (tid + 1536) * 8); \
        gload_lds16(gB0 + ko_, dB_ + tid * 8); \
        gload_lds16(gB1 + ko_, dB_ + (tid + 512) * 8); }

    f32x4 acc[4][4] = {};

    // prologue: stage tile 0 into buf 0, drain, barrier
    STAGE(0, 0);
    __syncthreads();

    int cur = 0;
    for (int t = 0; t < NT; ++t) {
        if (t + 1 < NT) STAGE(t + 1, cur ^ 1);   // issue next-tile loads FIRST

        const unsigned short* As = sA + cur * 16384;
        const unsigned short* Bs = sB + cur * 8192;
        bf16x8 af[2][4], bf_[2][4];
        #pragma unroll
        for (int ks = 0; ks < 2; ++ks) {
            const int kg = ks * 4 + hi;
            #pragma unroll
            for (int mi = 0; mi < 4; ++mi)
                af[ks][mi] = *(const bf16x8*)&As[(kg * 256 + wm * 64 + mi * 16 + lrow) * 8];
            #pragma unroll
            for (int ni = 0; ni < 4; ++ni)
                bf_[ks][ni] = *(const bf16x8*)&Bs[(kg * 128 + wn * 64 + ni * 16 + lrow) * 8];
        }
        __builtin_amdgcn_s_setprio(1);
        #pragma unroll
        for (int ks = 0; ks < 2; ++ks)
            #pragma unroll
            for (int mi = 0; mi < 4; ++mi)
                #pragma unroll
                for (int ni = 0; ni < 4; ++ni)
                    acc[mi][ni] = __builtin_amdgcn_mfma_f32_16x16x32_bf16(af[ks][mi], bf_[ks][ni], acc[mi][ni], 0, 0, 0);
        __builtin_amdgcn_s_setprio(0);
        __syncthreads();   // drain vmcnt (next tile resident) + publish
        cur ^= 1;
    }
#undef STAGE

    // epilogue: C/D layout row=hi*4+reg, col=lrow (verified m89)
    #pragma unroll
    for (int mi = 0; mi < 4; ++mi) {
        #pragma unroll
        for (int ni = 0; ni < 4; ++ni) {
            int gm0 = row0 + wm * 64 + mi * 16 + hi * 4;
            int gn  = col0 + wn * 64 + ni * 16 + lrow;
            #pragma unroll
            for (int r = 0; r < 4; ++r) {
                int gm = gm0 + r;
                float v = acc[mi][ni][r];
                if (EPI == 0) {
                    int which = gn >> 10, rem = gn & 1023;
                    int h = rem >> 6, d = rem & 63;
                    int bb = gm >> 11, t = gm & 2047;
                    if (which == 0) v *= 0.18033688011112042f;  // 0.125 * log2(e)
                    unsigned short* dst = (unsigned short*)(which == 0 ? out0 : (which == 1 ? out1 : out2));
                    dst[((size_t)(bb * NHEAD + h) * T_DIM + t) * HDIM + d] = f2bf(v);
                } else {
                    ((float*)out0)[(size_t)gm * N + gn] = v;
                }
            }
        }
    }
}

// ---------------- causal flash attention, 8 waves, dbuf + prefetch ----------------
// grid (8, 64); block processes q-tiles bx and 15-bx (uniform causal work: 34 tiles).
// Fixed-max softmax: S arrives in exp2 domain (Q pre-scaled by 0.125*log2e);
// P = exp2(S - 16). l via all-ones B-column MFMA from the same bf16 P as PV.
__global__ __launch_bounds__(512) void attn_k(
    const unsigned short* __restrict__ qb, const unsigned short* __restrict__ kb,
    const unsigned short* __restrict__ vtb, unsigned short* __restrict__ yb)
{
    __shared__ __align__(16) unsigned short Ks[2][64 * 64];   // [kv][d], chunk-swizzled
    __shared__ __align__(16) unsigned short Vts[2][64 * 64];  // [d][kv], chunk-swizzled
    __shared__ __align__(16) unsigned short Ps[8][16 * 72];

    const int tid = threadIdx.x, lane = tid & 63, wave = tid >> 6;
    const int bh = blockIdx.y;
    const int lrow = lane & 15, hi = lane >> 4, lk = hi * 8;
    const unsigned short* Kg  = kb  + (size_t)bh * T_DIM * HDIM;
    const unsigned short* Vtg = vtb + (size_t)bh * HDIM * T_DIM;

    // staging geometry: linear LDS dest, inverse-swizzled global source
    const int c = wave * 64 + lane;
    const int srow = c >> 3;
    const int sgp  = (c & 7) ^ (srow & 7);
    const size_t koff = (size_t)srow * 64 + sgp * 8;
    const size_t voff = (size_t)srow * T_DIM + sgp * 8;

    // ones B-fragment: B column 0 = 1.0 (row-sum extractor)
    bf16x8 bones;
    #pragma unroll
    for (int j = 0; j < 8; ++j) bones[j] = (lrow == 0) ? (short)0x3F80 : (short)0;

    #pragma unroll
    for (int pass = 0; pass < 2; ++pass) {
        const int bx = (pass == 0) ? (int)blockIdx.x : (15 - (int)blockIdx.x);
        const int q0 = bx * 128;
        const int jtmax = 2 * bx + 1;
        const int wrow0 = q0 + wave * 16;

        // Q fragments direct from global (pre-scaled into exp2 domain)
        const unsigned short* qrow = qb + ((size_t)bh * T_DIM + wrow0 + lrow) * HDIM;
        bf16x8 aq0 = *(const bf16x8*)(qrow + lk);
        bf16x8 aq1 = *(const bf16x8*)(qrow + 32 + lk);

        f32x4 o[4] = {};
        f32x4 ls = {};   // row-sums land in lanes with lrow==0

        gload_lds16(Kg + koff, &Ks[0][wave * 512]);
        gload_lds16(Vtg + voff, &Vts[0][wave * 512]);
        __syncthreads();

        int cur = 0;
        for (int jt = 0; jt <= jtmax; ++jt) {
            if (jt < jtmax) {   // prefetch next tile into alternate buffer
                gload_lds16(Kg + (size_t)(jt + 1) * 64 * HDIM + koff, &Ks[cur ^ 1][wave * 512]);
                gload_lds16(Vtg + (size_t)(jt + 1) * 64 + voff, &Vts[cur ^ 1][wave * 512]);
            }
            if (jt * 64 <= wrow0 + 15) {   // wave-uniform skip of fully-masked tiles
                // S = Q K^T  (exp2 domain)
                f32x4 s[4] = {};
                #pragma unroll
                for (int kk = 0; kk < 2; ++kk) {
                    bf16x8 aq = kk ? aq1 : aq0;
                    #pragma unroll
                    for (int n = 0; n < 4; ++n) {
                        const int row = n * 16 + lrow;
                        const int gc = (kk * 4 + hi) ^ (lrow & 7);
                        bf16x8 bk = *(const bf16x8*)&Ks[cur][row * 64 + gc * 8];
                        s[n] = __builtin_amdgcn_mfma_f32_16x16x32_bf16(aq, bk, s[n], 0, 0, 0);
                    }
                }
                // causal mask (diagonal tiles only)
                const int rbase = wrow0 + hi * 4;
                if (jt * 64 + 63 > wrow0) {
                    #pragma unroll
                    for (int n = 0; n < 4; ++n) {
                        const int kvcol = jt * 64 + n * 16 + lrow;
                        #pragma unroll
                        for (int r = 0; r < 4; ++r)
                            if (kvcol > rbase + r) s[n][r] = -1e30f;
                    }
                }
                // P = exp2(S - 16); write bf16 P to wave-private LDS
                #pragma unroll
                for (int n = 0; n < 4; ++n)
                    #pragma unroll
                    for (int r = 0; r < 4; ++r) {
                        float p = __builtin_amdgcn_exp2f(s[n][r] - 16.0f);
                        Ps[wave][(hi * 4 + r) * 72 + n * 16 + lrow] = f2bf(p);
                    }
                // O += P V ; ls += P * ones
                #pragma unroll
                for (int kk = 0; kk < 2; ++kk) {
                    bf16x8 pa = *(const bf16x8*)&Ps[wave][lrow * 72 + kk * 32 + lk];
                    #pragma unroll
                    for (int dn = 0; dn < 4; ++dn) {
                        const int row = dn * 16 + lrow;
                        const int gc = (kk * 4 + hi) ^ (lrow & 7);
                        bf16x8 bv = *(const bf16x8*)&Vts[cur][row * 64 + gc * 8];
                        o[dn] = __builtin_amdgcn_mfma_f32_16x16x32_bf16(pa, bv, o[dn], 0, 0, 0);
                    }
                    ls = __builtin_amdgcn_mfma_f32_16x16x32_bf16(pa, bones, ls, 0, 0, 0);
                }
            }
            __syncthreads();   // drains prefetch vmcnt; next tile ready
            cur ^= 1;
        }

        // epilogue: y[b*T + t][h*64 + d] bf16; l broadcast from lrow==0 lanes
        const int bb = bh >> 4, h = bh & 15;
        #pragma unroll
        for (int r = 0; r < 4; ++r) {
            float lsum = __shfl(ls[r], lane & 48);
            float inv = 1.0f / lsum;
            int t = q0 + wave * 16 + hi * 4 + r;
            size_t rowoff = ((size_t)(bb * T_DIM + t)) * 1024 + h * HDIM;
            #pragma unroll
            for (int dn = 0; dn < 4; ++dn)
                yb[rowoff + dn * 16 + lrow] = f2bf(o[dn][r] * inv);
        }
    }
}

extern "C" void kernel_launch(void* const* d_in, const int* in_sizes, int n_in,
                              void* d_out, int out_size, void* d_ws, size_t ws_size,
                              hipStream_t stream) {
    const float* x      = (const float*)d_in[0];   // [4,2048,1024]
    const float* w_attn = (const float*)d_in[1];   // [1024,3072]
    const float* w_proj = (const float*)d_in[2];   // [1024,1024]
    float* out = (float*)d_out;                    // [4,2048,1024]

    unsigned short* xb  = (unsigned short*)d_ws;           // [8192][1024]
    unsigned short* wat = xb  + (size_t)8192 * 1024;       // [3072][1024]
    unsigned short* wpt = wat + (size_t)3072 * 1024;       // [1024][1024]
    unsigned short* qb  = wpt + (size_t)1024 * 1024;       // [64][2048][64]
    unsigned short* kb  = qb  + (size_t)64 * 2048 * 64;
    unsigned short* vb  = kb  + (size_t)64 * 2048 * 64;
    unsigned short* yb  = vb  + (size_t)64 * 2048 * 64;    // [8192][1024]
    unsigned short* vt  = xb;   // reuse xb (dead after QKV GEMM) for V^T [64][64][2048]

    // allow 96 KiB dynamic LDS for the GEMM (idempotent, capture-safe host call)
    (void)hipFuncSetAttribute((const void*)gemm_bt_k<0>,
                              hipFuncAttributeMaxDynamicSharedMemorySize, 98304);
    (void)hipFuncSetAttribute((const void*)gemm_bt_k<1>,
                              hipFuncAttributeMaxDynamicSharedMemorySize, 98304);

    cvt_bf16_k<<<8192, 256, 0, stream>>>(x, xb, 8192 * 1024);
    transpose_wb_k<<<dim3(96, 32), 256, 0, stream>>>(w_attn, wat, 1024, 3072);
    transpose_wb_k<<<dim3(32, 32), 256, 0, stream>>>(w_proj, wpt, 1024, 1024);

    gemm_bt_k<0><<<dim3(24, 32), 512, 98304, stream>>>(xb, wat, qb, kb, vb, 8192, 3072, 1024);
    transpose_v_k<<<dim3(32, 64), 256, 0, stream>>>(vb, vt);
    attn_k<<<dim3(8, 64), 512, 0, stream>>>(qb, kb, vt, yb);
    gemm_bt_k<1><<<dim3(8, 32), 512, 98304, stream>>>(yb, wpt, out, nullptr, nullptr, 8192, 1024, 1024);
}

// Round 7
// 184.035 us; speedup vs baseline: 1.2760x; 1.2760x over previous
//
#include <hip/hip_runtime.h>
#include <hip/hip_bf16.h>

// B=4, T=2048, C=1024, H=16, D=64. f32 in/out; bf16 MFMA internally.

typedef __attribute__((ext_vector_type(8))) short bf16x8;
typedef __attribute__((ext_vector_type(4))) float f32x4;

#define T_DIM 2048
#define NHEAD 16
#define HDIM  64

__device__ __forceinline__ unsigned short f2bf(float f) {
    union { float f; unsigned int u; } v; v.f = f;
    unsigned int r = v.u + 0x7fffu + ((v.u >> 16) & 1u);   // RNE
    return (unsigned short)(r >> 16);
}

__device__ __forceinline__ void gload_lds16(const void* g, void* l) {
    __builtin_amdgcn_global_load_lds(
        (const __attribute__((address_space(1))) void*)g,
        (__attribute__((address_space(3))) void*)l,
        16, 0, 0);
}

// ---------------- f32 -> bf16 convert (vectorized) ----------------
__global__ void cvt_bf16_k(const float* __restrict__ src, unsigned short* __restrict__ dst, int n) {
    int i = (blockIdx.x * blockDim.x + threadIdx.x) * 4;
    if (i < n) {
        float4 v = *(const float4*)(src + i);
        ushort4 o; o.x = f2bf(v.x); o.y = f2bf(v.y); o.z = f2bf(v.z); o.w = f2bf(v.w);
        *(ushort4*)(dst + i) = o;
    }
}

// ---------------- transpose f32 [R][Cc] -> bf16 [Cc][R] ----------------
__global__ void transpose_wb_k(const float* __restrict__ src, unsigned short* __restrict__ dst,
                               int R, int Cc) {
    __shared__ float tile[32][33];
    int c0 = blockIdx.x * 32, r0 = blockIdx.y * 32;
    int tx = threadIdx.x & 31, ty = threadIdx.x >> 5;   // 32 x 8
    #pragma unroll
    for (int i = 0; i < 32; i += 8)
        tile[ty + i][tx] = src[(size_t)(r0 + ty + i) * Cc + c0 + tx];
    __syncthreads();
    #pragma unroll
    for (int i = 0; i < 32; i += 8)
        dst[(size_t)(c0 + ty + i) * R + r0 + tx] = f2bf(tile[tx][ty + i]);
}

// ---------------- bf16 transpose V [bh][t][d] -> V^T [bh][d][t] ----------------
__global__ __launch_bounds__(256) void transpose_v_k(const unsigned short* __restrict__ vb,
                                                     unsigned short* __restrict__ vt) {
    __shared__ __align__(16) unsigned short L[64 * 72];
    const int bh = blockIdx.y, t0 = blockIdx.x * 64;
    const int tid = threadIdx.x;
    const unsigned short* src = vb + ((size_t)bh * T_DIM + t0) * HDIM;
    #pragma unroll
    for (int i = 0; i < 2; ++i) {
        int cc = tid + i * 256;            // 0..511
        int r = cc >> 3, g = cc & 7;
        *(uint4*)&L[r * 72 + g * 8] = *(const uint4*)(src + r * 64 + g * 8);
    }
    __syncthreads();
    unsigned short* dst = vt + (size_t)bh * HDIM * T_DIM + t0;
    #pragma unroll
    for (int i = 0; i < 2; ++i) {
        int cc = tid + i * 256;
        int d = cc >> 3, gt = cc & 7;
        unsigned short tmp[8];
        #pragma unroll
        for (int j = 0; j < 8; ++j) tmp[j] = L[(gt * 8 + j) * 72 + d];
        *(uint4*)(dst + (size_t)d * T_DIM + gt * 8) = *(uint4*)tmp;
    }
}

// ---------------- 256x128 ring-3 counted-vmcnt GEMM, C = A[M,K] * Bt[N,K]^T ----------------
// 8 waves (4M x 2N), per-wave 64x64 out. BK=64. LDS: 3 K-tile slots x (A 32K + B 16K) = 144 KiB.
// Iter t: STAGE(t+2 -> slot (t+2)%3) first; 16 ds_read_b128 (XOR-swizzled, conflict-free);
// 32 MFMA (setprio); s_waitcnt vmcnt(6) [t+1 resident, t+2 in flight]; raw s_barrier.
// Staging: chunk c=(row, g); source k-chunk = g^(row&7); reader uses kc^(row&7)  [rule #21].
// Coalesced: each wave-load = 8 rows x 128B contiguous.
// EPI==0: scatter bf16 q/k/v [B,H,T,D]; q scaled by 0.125*log2(e). EPI==1: f32 [M,N].
template<int EPI>
__global__ __launch_bounds__(512, 2) void gemm_bt_k(
    const unsigned short* __restrict__ A, const unsigned short* __restrict__ Bt,
    void* __restrict__ out0, void* __restrict__ out1, void* __restrict__ out2,
    int M, int N, int K)
{
    extern __shared__ __align__(16) unsigned short smem[];
    unsigned short* sA = smem;           // [3][256][8ch][8] = 49152 shorts (96 KiB)
    unsigned short* sB = smem + 49152;   // [3][128][8ch][8] = 24576 shorts (48 KiB)

    const int tid = threadIdx.x, lane = tid & 63, wave = tid >> 6;
    const int wm = wave >> 1, wn = wave & 1;     // 4M x 2N
    const int lrow = lane & 15, hi = lane >> 4;

    // bijective XCD-chunked swizzle (nwg % 8 == 0 for our grids)
    const int nwg = gridDim.x * gridDim.y;
    const int lin = blockIdx.y * gridDim.x + blockIdx.x;
    const int lin2 = (lin & 7) * (nwg >> 3) + (lin >> 3);
    const int bxg = lin2 % gridDim.x, byg = lin2 / gridDim.x;
    const int row0 = byg * 256, col0 = bxg * 128;

    // staging sources: chunk c -> row c>>3, lds k-chunk c&7, global k-chunk (c&7)^(row&7).
    // (c&7) and (row&7) are invariant under c += 512 -> one gk for all loads.
    const int arow = tid >> 3;
    const int gk = ((tid & 7) ^ (arow & 7)) * 8;
    const unsigned short* gA0 = A + (size_t)(row0 + arow) * K + gk;         // rows 0..63
    const unsigned short* gA1 = A + (size_t)(row0 + arow + 64) * K + gk;
    const unsigned short* gA2 = A + (size_t)(row0 + arow + 128) * K + gk;
    const unsigned short* gA3 = A + (size_t)(row0 + arow + 192) * K + gk;
    const unsigned short* gB0 = Bt + (size_t)(col0 + arow) * K + gk;
    const unsigned short* gB1 = Bt + (size_t)(col0 + arow + 64) * K + gk;

    const int NT = K >> 6;   // K-tiles of 64

#define STAGE(ts, sl) { const size_t ko_ = (size_t)(ts) * 64; \
        unsigned short* dA_ = sA + (sl) * 16384; \
        unsigned short* dB_ = sB + (sl) * 8192; \
        gload_lds16(gA0 + ko_, dA_ + tid * 8); \
        gload_lds16(gA1 + ko_, dA_ + (tid + 512) * 8); \
        gload_lds16(gA2 + ko_, dA_ + (tid + 1024) * 8); \
        gload_lds16(gA3 + ko_, dA_ + (tid + 1536) * 8); \
        gload_lds16(gB0 + ko_, dB_ + tid * 8); \
        gload_lds16(gB1 + ko_, dB_ + (tid + 512) * 8); }

    f32x4 acc[4][4] = {};

    // prologue: stage tiles 0,1; counted wait for tile 0 only
    STAGE(0, 0);
    STAGE(1, 1);
    asm volatile("s_waitcnt vmcnt(6)" ::: "memory");
    __builtin_amdgcn_s_barrier();
    __builtin_amdgcn_sched_barrier(0);

    int slot = 0;
    for (int t = 0; t < NT; ++t) {
        if (t + 2 < NT) {
            const int s2 = (slot + 2 >= 3) ? slot - 1 : slot + 2;
            STAGE(t + 2, s2);
        }
        const unsigned short* As = sA + slot * 16384;
        const unsigned short* Bs = sB + slot * 8192;
        bf16x8 af[2][4], bf_[2][4];
        #pragma unroll
        for (int ks = 0; ks < 2; ++ks) {
            const int kc = (ks * 4 + hi) ^ (lrow & 7);   // XOR readback
            #pragma unroll
            for (int mi = 0; mi < 4; ++mi)
                af[ks][mi] = *(const bf16x8*)&As[((wm * 64 + mi * 16 + lrow) * 8 + kc) * 8];
            #pragma unroll
            for (int ni = 0; ni < 4; ++ni)
                bf_[ks][ni] = *(const bf16x8*)&Bs[((wn * 64 + ni * 16 + lrow) * 8 + kc) * 8];
        }
        __builtin_amdgcn_s_setprio(1);
        #pragma unroll
        for (int ks = 0; ks < 2; ++ks)
            #pragma unroll
            for (int mi = 0; mi < 4; ++mi)
                #pragma unroll
                for (int ni = 0; ni < 4; ++ni)
                    acc[mi][ni] = __builtin_amdgcn_mfma_f32_16x16x32_bf16(af[ks][mi], bf_[ks][ni], acc[mi][ni], 0, 0, 0);
        __builtin_amdgcn_s_setprio(0);
        // counted boundary: tile t+1 resident (only t+2's 6 loads may be outstanding)
        if (t + 2 < NT) { asm volatile("s_waitcnt vmcnt(6)" ::: "memory"); }
        else           { asm volatile("s_waitcnt vmcnt(0)" ::: "memory"); }
        __builtin_amdgcn_s_barrier();
        __builtin_amdgcn_sched_barrier(0);
        slot = (slot + 1 >= 3) ? 0 : slot + 1;
    }
#undef STAGE

    // epilogue: C/D layout row=hi*4+reg, col=lrow (verified m89)
    #pragma unroll
    for (int mi = 0; mi < 4; ++mi) {
        #pragma unroll
        for (int ni = 0; ni < 4; ++ni) {
            int gm0 = row0 + wm * 64 + mi * 16 + hi * 4;
            int gn  = col0 + wn * 64 + ni * 16 + lrow;
            #pragma unroll
            for (int r = 0; r < 4; ++r) {
                int gm = gm0 + r;
                float v = acc[mi][ni][r];
                if (EPI == 0) {
                    int which = gn >> 10, rem = gn & 1023;
                    int h = rem >> 6, d = rem & 63;
                    int bb = gm >> 11, t = gm & 2047;
                    if (which == 0) v *= 0.18033688011112042f;  // 0.125 * log2(e)
                    unsigned short* dst = (unsigned short*)(which == 0 ? out0 : (which == 1 ? out1 : out2));
                    dst[((size_t)(bb * NHEAD + h) * T_DIM + t) * HDIM + d] = f2bf(v);
                } else {
                    ((float*)out0)[(size_t)gm * N + gn] = v;
                }
            }
        }
    }
}

// ---------------- causal flash attention, 8 waves, dbuf + prefetch ----------------
// grid (8, 64); block processes q-tiles bx and 15-bx (uniform causal work: 34 tiles).
// Fixed-max softmax: S arrives in exp2 domain (Q pre-scaled by 0.125*log2e);
// P = exp2(S - 16). l via all-ones B-column MFMA from the same bf16 P as PV.
__global__ __launch_bounds__(512) void attn_k(
    const unsigned short* __restrict__ qb, const unsigned short* __restrict__ kb,
    const unsigned short* __restrict__ vtb, unsigned short* __restrict__ yb)
{
    __shared__ __align__(16) unsigned short Ks[2][64 * 64];   // [kv][d], chunk-swizzled
    __shared__ __align__(16) unsigned short Vts[2][64 * 64];  // [d][kv], chunk-swizzled
    __shared__ __align__(16) unsigned short Ps[8][16 * 72];

    const int tid = threadIdx.x, lane = tid & 63, wave = tid >> 6;
    const int bh = blockIdx.y;
    const int lrow = lane & 15, hi = lane >> 4, lk = hi * 8;
    const unsigned short* Kg  = kb  + (size_t)bh * T_DIM * HDIM;
    const unsigned short* Vtg = vtb + (size_t)bh * HDIM * T_DIM;

    // staging geometry: linear LDS dest, inverse-swizzled global source
    const int c = wave * 64 + lane;
    const int srow = c >> 3;
    const int sgp  = (c & 7) ^ (srow & 7);
    const size_t koff = (size_t)srow * 64 + sgp * 8;
    const size_t voff = (size_t)srow * T_DIM + sgp * 8;

    // ones B-fragment: B column 0 = 1.0 (row-sum extractor)
    bf16x8 bones;
    #pragma unroll
    for (int j = 0; j < 8; ++j) bones[j] = (lrow == 0) ? (short)0x3F80 : (short)0;

    #pragma unroll
    for (int pass = 0; pass < 2; ++pass) {
        const int bx = (pass == 0) ? (int)blockIdx.x : (15 - (int)blockIdx.x);
        const int q0 = bx * 128;
        const int jtmax = 2 * bx + 1;
        const int wrow0 = q0 + wave * 16;

        // Q fragments direct from global (pre-scaled into exp2 domain)
        const unsigned short* qrow = qb + ((size_t)bh * T_DIM + wrow0 + lrow) * HDIM;
        bf16x8 aq0 = *(const bf16x8*)(qrow + lk);
        bf16x8 aq1 = *(const bf16x8*)(qrow + 32 + lk);

        f32x4 o[4] = {};
        f32x4 ls = {};   // row-sums land in lanes with lrow==0

        gload_lds16(Kg + koff, &Ks[0][wave * 512]);
        gload_lds16(Vtg + voff, &Vts[0][wave * 512]);
        __syncthreads();

        int cur = 0;
        for (int jt = 0; jt <= jtmax; ++jt) {
            if (jt < jtmax) {   // prefetch next tile into alternate buffer
                gload_lds16(Kg + (size_t)(jt + 1) * 64 * HDIM + koff, &Ks[cur ^ 1][wave * 512]);
                gload_lds16(Vtg + (size_t)(jt + 1) * 64 + voff, &Vts[cur ^ 1][wave * 512]);
            }
            if (jt * 64 <= wrow0 + 15) {   // wave-uniform skip of fully-masked tiles
                // S = Q K^T  (exp2 domain)
                f32x4 s[4] = {};
                #pragma unroll
                for (int kk = 0; kk < 2; ++kk) {
                    bf16x8 aq = kk ? aq1 : aq0;
                    #pragma unroll
                    for (int n = 0; n < 4; ++n) {
                        const int row = n * 16 + lrow;
                        const int gc = (kk * 4 + hi) ^ (lrow & 7);
                        bf16x8 bk = *(const bf16x8*)&Ks[cur][row * 64 + gc * 8];
                        s[n] = __builtin_amdgcn_mfma_f32_16x16x32_bf16(aq, bk, s[n], 0, 0, 0);
                    }
                }
                // causal mask (diagonal tiles only)
                const int rbase = wrow0 + hi * 4;
                if (jt * 64 + 63 > wrow0) {
                    #pragma unroll
                    for (int n = 0; n < 4; ++n) {
                        const int kvcol = jt * 64 + n * 16 + lrow;
                        #pragma unroll
                        for (int r = 0; r < 4; ++r)
                            if (kvcol > rbase + r) s[n][r] = -1e30f;
                    }
                }
                // P = exp2(S - 16); write bf16 P to wave-private LDS
                #pragma unroll
                for (int n = 0; n < 4; ++n)
                    #pragma unroll
                    for (int r = 0; r < 4; ++r) {
                        float p = __builtin_amdgcn_exp2f(s[n][r] - 16.0f);
                        Ps[wave][(hi * 4 + r) * 72 + n * 16 + lrow] = f2bf(p);
                    }
                // O += P V ; ls += P * ones
                #pragma unroll
                for (int kk = 0; kk < 2; ++kk) {
                    bf16x8 pa = *(const bf16x8*)&Ps[wave][lrow * 72 + kk * 32 + lk];
                    #pragma unroll
                    for (int dn = 0; dn < 4; ++dn) {
                        const int row = dn * 16 + lrow;
                        const int gc = (kk * 4 + hi) ^ (lrow & 7);
                        bf16x8 bv = *(const bf16x8*)&Vts[cur][row * 64 + gc * 8];
                        o[dn] = __builtin_amdgcn_mfma_f32_16x16x32_bf16(pa, bv, o[dn], 0, 0, 0);
                    }
                    ls = __builtin_amdgcn_mfma_f32_16x16x32_bf16(pa, bones, ls, 0, 0, 0);
                }
            }
            __syncthreads();   // drains prefetch vmcnt; next tile ready
            cur ^= 1;
        }

        // epilogue: y[b*T + t][h*64 + d] bf16; l broadcast from lrow==0 lanes
        const int bb = bh >> 4, h = bh & 15;
        #pragma unroll
        for (int r = 0; r < 4; ++r) {
            float lsum = __shfl(ls[r], lane & 48);
            float inv = 1.0f / lsum;
            int t = q0 + wave * 16 + hi * 4 + r;
            size_t rowoff = ((size_t)(bb * T_DIM + t)) * 1024 + h * HDIM;
            #pragma unroll
            for (int dn = 0; dn < 4; ++dn)
                yb[rowoff + dn * 16 + lrow] = f2bf(o[dn][r] * inv);
        }
    }
}

extern "C" void kernel_launch(void* const* d_in, const int* in_sizes, int n_in,
                              void* d_out, int out_size, void* d_ws, size_t ws_size,
                              hipStream_t stream) {
    const float* x      = (const float*)d_in[0];   // [4,2048,1024]
    const float* w_attn = (const float*)d_in[1];   // [1024,3072]
    const float* w_proj = (const float*)d_in[2];   // [1024,1024]
    float* out = (float*)d_out;                    // [4,2048,1024]

    unsigned short* xb  = (unsigned short*)d_ws;           // [8192][1024]
    unsigned short* wat = xb  + (size_t)8192 * 1024;       // [3072][1024]
    unsigned short* wpt = wat + (size_t)3072 * 1024;       // [1024][1024]
    unsigned short* qb  = wpt + (size_t)1024 * 1024;       // [64][2048][64]
    unsigned short* kb  = qb  + (size_t)64 * 2048 * 64;
    unsigned short* vb  = kb  + (size_t)64 * 2048 * 64;
    unsigned short* yb  = vb  + (size_t)64 * 2048 * 64;    // [8192][1024]
    unsigned short* vt  = xb;   // reuse xb (dead after QKV GEMM) for V^T [64][64][2048]

    // allow 144 KiB dynamic LDS for the GEMM (idempotent, capture-safe host call)
    (void)hipFuncSetAttribute((const void*)gemm_bt_k<0>,
                              hipFuncAttributeMaxDynamicSharedMemorySize, 147456);
    (void)hipFuncSetAttribute((const void*)gemm_bt_k<1>,
                              hipFuncAttributeMaxDynamicSharedMemorySize, 147456);

    cvt_bf16_k<<<8192, 256, 0, stream>>>(x, xb, 8192 * 1024);
    transpose_wb_k<<<dim3(96, 32), 256, 0, stream>>>(w_attn, wat, 1024, 3072);
    transpose_wb_k<<<dim3(32, 32), 256, 0, stream>>>(w_proj, wpt, 1024, 1024);

    gemm_bt_k<0><<<dim3(24, 32), 512, 147456, stream>>>(xb, wat, qb, kb, vb, 8192, 3072, 1024);
    transpose_v_k<<<dim3(32, 64), 256, 0, stream>>>(vb, vt);
    attn_k<<<dim3(8, 64), 512, 0, stream>>>(qb, kb, vt, yb);
    gemm_bt_k<1><<<dim3(8, 32), 512, 147456, stream>>>(yb, wpt, out, nullptr, nullptr, 8192, 1024, 1024);
}

// Round 8
// 172.549 us; speedup vs baseline: 1.3609x; 1.0666x over previous
//
#include <hip/hip_runtime.h>
#include <hip/hip_bf16.h>

// B=4, T=2048, C=1024, H=16, D=64. f32 in/out; bf16 MFMA internally.

typedef __attribute__((ext_vector_type(8))) short bf16x8;
typedef __attribute__((ext_vector_type(4))) float f32x4;
typedef __attribute__((ext_vector_type(16))) float f32x16;

#define T_DIM 2048
#define NHEAD 16
#define HDIM  64

__device__ __forceinline__ unsigned short f2bf(float f) {
    union { float f; unsigned int u; } v; v.f = f;
    unsigned int r = v.u + 0x7fffu + ((v.u >> 16) & 1u);   // RNE
    return (unsigned short)(r >> 16);
}

__device__ __forceinline__ unsigned cvtpk_bf16(float lo, float hi) {
    unsigned r;
    asm("v_cvt_pk_bf16_f32 %0, %1, %2" : "=v"(r) : "v"(lo), "v"(hi));
    return r;
}
__device__ __forceinline__ void pl32swap(unsigned &x, unsigned &y) {
    asm("v_permlane32_swap_b32 %0, %1" : "+v"(x), "+v"(y));
}
__device__ __forceinline__ bf16x8 mk8(unsigned w0, unsigned w1, unsigned w2, unsigned w3) {
    union { unsigned u[4]; bf16x8 v; } p;
    p.u[0] = w0; p.u[1] = w1; p.u[2] = w2; p.u[3] = w3;
    return p.v;
}

__device__ __forceinline__ void gload_lds16(const void* g, void* l) {
    __builtin_amdgcn_global_load_lds(
        (const __attribute__((address_space(1))) void*)g,
        (__attribute__((address_space(3))) void*)l,
        16, 0, 0);
}

// ---------------- f32 -> bf16 convert (vectorized) ----------------
__global__ void cvt_bf16_k(const float* __restrict__ src, unsigned short* __restrict__ dst, int n) {
    int i = (blockIdx.x * blockDim.x + threadIdx.x) * 4;
    if (i < n) {
        float4 v = *(const float4*)(src + i);
        ushort4 o; o.x = f2bf(v.x); o.y = f2bf(v.y); o.z = f2bf(v.z); o.w = f2bf(v.w);
        *(ushort4*)(dst + i) = o;
    }
}

// ---------------- transpose f32 [R][Cc] -> bf16 [Cc][R] ----------------
__global__ void transpose_wb_k(const float* __restrict__ src, unsigned short* __restrict__ dst,
                               int R, int Cc) {
    __shared__ float tile[32][33];
    int c0 = blockIdx.x * 32, r0 = blockIdx.y * 32;
    int tx = threadIdx.x & 31, ty = threadIdx.x >> 5;   // 32 x 8
    #pragma unroll
    for (int i = 0; i < 32; i += 8)
        tile[ty + i][tx] = src[(size_t)(r0 + ty + i) * Cc + c0 + tx];
    __syncthreads();
    #pragma unroll
    for (int i = 0; i < 32; i += 8)
        dst[(size_t)(c0 + ty + i) * R + r0 + tx] = f2bf(tile[tx][ty + i]);
}

// ---------------- 256x128 ring-3 counted-vmcnt GEMM, C = A[M,K] * Bt[N,K]^T ----------------
// (unchanged from R7 except EPI==0 epilogue: K/V written in chunk-major attn layouts)
template<int EPI>
__global__ __launch_bounds__(512, 2) void gemm_bt_k(
    const unsigned short* __restrict__ A, const unsigned short* __restrict__ Bt,
    void* __restrict__ out0, void* __restrict__ out1, void* __restrict__ out2,
    int M, int N, int K)
{
    extern __shared__ __align__(16) unsigned short smem[];
    unsigned short* sA = smem;           // [3][256][8ch][8] = 49152 shorts (96 KiB)
    unsigned short* sB = smem + 49152;   // [3][128][8ch][8] = 24576 shorts (48 KiB)

    const int tid = threadIdx.x, lane = tid & 63, wave = tid >> 6;
    const int wm = wave >> 1, wn = wave & 1;     // 4M x 2N
    const int lrow = lane & 15, hi = lane >> 4;

    const int nwg = gridDim.x * gridDim.y;
    const int lin = blockIdx.y * gridDim.x + blockIdx.x;
    const int lin2 = (lin & 7) * (nwg >> 3) + (lin >> 3);
    const int bxg = lin2 % gridDim.x, byg = lin2 / gridDim.x;
    const int row0 = byg * 256, col0 = bxg * 128;

    const int arow = tid >> 3;
    const int gk = ((tid & 7) ^ (arow & 7)) * 8;
    const unsigned short* gA0 = A + (size_t)(row0 + arow) * K + gk;
    const unsigned short* gA1 = A + (size_t)(row0 + arow + 64) * K + gk;
    const unsigned short* gA2 = A + (size_t)(row0 + arow + 128) * K + gk;
    const unsigned short* gA3 = A + (size_t)(row0 + arow + 192) * K + gk;
    const unsigned short* gB0 = Bt + (size_t)(col0 + arow) * K + gk;
    const unsigned short* gB1 = Bt + (size_t)(col0 + arow + 64) * K + gk;

    const int NT = K >> 6;

#define STAGE(ts, sl) { const size_t ko_ = (size_t)(ts) * 64; \
        unsigned short* dA_ = sA + (sl) * 16384; \
        unsigned short* dB_ = sB + (sl) * 8192; \
        gload_lds16(gA0 + ko_, dA_ + tid * 8); \
        gload_lds16(gA1 + ko_, dA_ + (tid + 512) * 8); \
        gload_lds16(gA2 + ko_, dA_ + (tid + 1024) * 8); \
        gload_lds16(gA3 + ko_, dA_ + (tid + 1536) * 8); \
        gload_lds16(gB0 + ko_, dB_ + tid * 8); \
        gload_lds16(gB1 + ko_, dB_ + (tid + 512) * 8); }

    f32x4 acc[4][4] = {};

    STAGE(0, 0);
    STAGE(1, 1);
    asm volatile("s_waitcnt vmcnt(6)" ::: "memory");
    __builtin_amdgcn_s_barrier();
    __builtin_amdgcn_sched_barrier(0);

    int slot = 0;
    for (int t = 0; t < NT; ++t) {
        if (t + 2 < NT) {
            const int s2 = (slot + 2 >= 3) ? slot - 1 : slot + 2;
            STAGE(t + 2, s2);
        }
        const unsigned short* As = sA + slot * 16384;
        const unsigned short* Bs = sB + slot * 8192;
        bf16x8 af[2][4], bf_[2][4];
        #pragma unroll
        for (int ks = 0; ks < 2; ++ks) {
            const int kc = (ks * 4 + hi) ^ (lrow & 7);
            #pragma unroll
            for (int mi = 0; mi < 4; ++mi)
                af[ks][mi] = *(const bf16x8*)&As[((wm * 64 + mi * 16 + lrow) * 8 + kc) * 8];
            #pragma unroll
            for (int ni = 0; ni < 4; ++ni)
                bf_[ks][ni] = *(const bf16x8*)&Bs[((wn * 64 + ni * 16 + lrow) * 8 + kc) * 8];
        }
        __builtin_amdgcn_s_setprio(1);
        #pragma unroll
        for (int ks = 0; ks < 2; ++ks)
            #pragma unroll
            for (int mi = 0; mi < 4; ++mi)
                #pragma unroll
                for (int ni = 0; ni < 4; ++ni)
                    acc[mi][ni] = __builtin_amdgcn_mfma_f32_16x16x32_bf16(af[ks][mi], bf_[ks][ni], acc[mi][ni], 0, 0, 0);
        __builtin_amdgcn_s_setprio(0);
        if (t + 2 < NT) { asm volatile("s_waitcnt vmcnt(6)" ::: "memory"); }
        else           { asm volatile("s_waitcnt vmcnt(0)" ::: "memory"); }
        __builtin_amdgcn_s_barrier();
        __builtin_amdgcn_sched_barrier(0);
        slot = (slot + 1 >= 3) ? 0 : slot + 1;
    }
#undef STAGE

    // epilogue: C/D layout row=hi*4+reg, col=lrow (verified m89)
    #pragma unroll
    for (int mi = 0; mi < 4; ++mi) {
        #pragma unroll
        for (int ni = 0; ni < 4; ++ni) {
            int gm0 = row0 + wm * 64 + mi * 16 + hi * 4;
            int gn  = col0 + wn * 64 + ni * 16 + lrow;
            #pragma unroll
            for (int r = 0; r < 4; ++r) {
                int gm = gm0 + r;
                float v = acc[mi][ni][r];
                if (EPI == 0) {
                    int which = gn >> 10, rem = gn & 1023;
                    int h = rem >> 6, d = rem & 63;
                    int bb = gm >> 11, t = gm & 2047;
                    int bh = bb * NHEAD + h;
                    if (which == 0) {        // Q natural [bh][t][d], exp2-domain scale
                        ((unsigned short*)out0)[((size_t)bh * T_DIM + t) * HDIM + d] =
                            f2bf(v * 0.18033688011112042f);
                    } else if (which == 1) { // K chunk-major [bh][t/64][(d>>3)*64 + t%64][d&7]
                        ((unsigned short*)out1)[(size_t)(bh * 32 + (t >> 6)) * 4096 +
                            (size_t)((d >> 3) * 64 + (t & 63)) * 8 + (d & 7)] = f2bf(v);
                    } else {                 // V chunk-major-transposed [bh][t/64][((t>>3)&7)*64 + d][t&7]
                        ((unsigned short*)out2)[(size_t)(bh * 32 + (t >> 6)) * 4096 +
                            (size_t)(((t >> 3) & 7) * 64 + d) * 8 + (t & 7)] = f2bf(v);
                    }
                } else {
                    ((float*)out0)[(size_t)gm * N + gn] = v;
                }
            }
        }
    }
}

// ---------------- causal flash attention: 8 waves x 32 q-rows, swapped 32x32 QK^T ----------------
// grid (4, 64); block does q-tiles (bx, 7-bx) of 256 rows each -> uniform 36 kv-tiles.
// S^T = mfma_32x32x16(K, Q): lane holds col q=lane&31, rows kv=(r&3)+8*(r>>2)+4*(lane>>5).
// P = exp2(S-16) in regs; cvt_pk + permlane32_swap builds PV A-frags; no P LDS.
// K/V staged from chunk-major globals; all LDS reads contiguous per 32-lane half.
__global__ __launch_bounds__(512) void attn_k(
    const unsigned short* __restrict__ qb, const unsigned short* __restrict__ kcm,
    const unsigned short* __restrict__ vcm, unsigned short* __restrict__ yb)
{
    __shared__ __align__(16) unsigned short Ks[2][4096];
    __shared__ __align__(16) unsigned short Vs[2][4096];

    const int tid = threadIdx.x, lane = tid & 63, wave = tid >> 6;
    const int bh = blockIdx.y;
    const int q32 = lane & 31, hi32 = lane >> 5;
    const unsigned short* Kg = kcm + (size_t)bh * 32 * 4096;
    const unsigned short* Vg = vcm + (size_t)bh * 32 * 4096;

    #pragma unroll
    for (int pass = 0; pass < 2; ++pass) {
        const int bxx = (pass == 0) ? (int)blockIdx.x : (7 - (int)blockIdx.x);
        const int ntiles = 4 * bxx + 4;
        const int q0w = bxx * 256 + wave * 32;
        const int qg = q0w + q32;

        // Q B-fragments direct from global (pre-scaled into exp2 domain)
        const unsigned short* qrow = qb + ((size_t)bh * T_DIM + q0w + q32) * HDIM;
        bf16x8 qf[4];
        #pragma unroll
        for (int kc = 0; kc < 4; ++kc)
            qf[kc] = *(const bf16x8*)(qrow + kc * 16 + hi32 * 8);

        f32x16 o0 = {}, o1 = {};
        float lsum = 0.f;

        gload_lds16(Kg + tid * 8, &Ks[0][tid * 8]);
        gload_lds16(Vg + tid * 8, &Vs[0][tid * 8]);
        __syncthreads();

        int cur = 0;
        for (int jt = 0; jt < ntiles; ++jt) {
            if (jt + 1 < ntiles) {
                gload_lds16(Kg + (size_t)(jt + 1) * 4096 + tid * 8, &Ks[cur ^ 1][tid * 8]);
                gload_lds16(Vg + (size_t)(jt + 1) * 4096 + tid * 8, &Vs[cur ^ 1][tid * 8]);
            }
            if (jt * 64 <= q0w + 31) {   // wave-uniform skip of fully-masked tiles
                // S^T = K · Q  (exp2 domain)
                f32x16 s0 = {}, s1 = {};
                #pragma unroll
                for (int kc = 0; kc < 4; ++kc) {
                    bf16x8 a0 = *(const bf16x8*)&Ks[cur][((kc * 2 + hi32) * 64 + q32) * 8];
                    bf16x8 a1 = *(const bf16x8*)&Ks[cur][((kc * 2 + hi32) * 64 + 32 + q32) * 8];
                    s0 = __builtin_amdgcn_mfma_f32_32x32x16_bf16(a0, qf[kc], s0, 0, 0, 0);
                    s1 = __builtin_amdgcn_mfma_f32_32x32x16_bf16(a1, qf[kc], s1, 0, 0, 0);
                }
                // causal mask (diagonal tiles only); kv = jt*64 + blk*32 + crow(r)
                if (jt * 64 + 63 > q0w) {
                    #pragma unroll
                    for (int r = 0; r < 16; ++r) {
                        int kv0 = jt * 64 + (r & 3) + 8 * (r >> 2) + 4 * hi32;
                        if (kv0 > qg)      s0[r] = -1e30f;
                        if (kv0 + 32 > qg) s1[r] = -1e30f;
                    }
                }
                // P = exp2(S-16); pack to bf16; permlane-assemble PV A-frags
                bf16x8 pa[4];
                #pragma unroll
                for (int blk = 0; blk < 2; ++blk) {
                    float p_[16]; unsigned w_[8];
                    #pragma unroll
                    for (int i = 0; i < 16; ++i) {
                        float sv = blk ? s1[i] : s0[i];
                        p_[i] = __builtin_amdgcn_exp2f(sv - 16.0f);
                        lsum += p_[i];
                    }
                    #pragma unroll
                    for (int i = 0; i < 8; ++i) w_[i] = cvtpk_bf16(p_[2 * i], p_[2 * i + 1]);
                    pl32swap(w_[0], w_[2]); pl32swap(w_[1], w_[3]);
                    pl32swap(w_[4], w_[6]); pl32swap(w_[5], w_[7]);
                    pa[blk * 2]     = mk8(w_[0], w_[1], w_[2], w_[3]);
                    pa[blk * 2 + 1] = mk8(w_[4], w_[5], w_[6], w_[7]);
                }
                // O += P V
                #pragma unroll
                for (int kvc = 0; kvc < 4; ++kvc) {
                    bf16x8 b0 = *(const bf16x8*)&Vs[cur][((kvc * 2 + hi32) * 64 + q32) * 8];
                    bf16x8 b1 = *(const bf16x8*)&Vs[cur][((kvc * 2 + hi32) * 64 + 32 + q32) * 8];
                    o0 = __builtin_amdgcn_mfma_f32_32x32x16_bf16(pa[kvc], b0, o0, 0, 0, 0);
                    o1 = __builtin_amdgcn_mfma_f32_32x32x16_bf16(pa[kvc], b1, o1, 0, 0, 0);
                }
            }
            __syncthreads();   // drains prefetch; next tile ready
            cur ^= 1;
        }

        // l: own-half sum + partner-half via permlane pair
        {
            unsigned la = __float_as_uint(lsum), lb = __float_as_uint(lsum);
            pl32swap(la, lb);
            lsum = __uint_as_float(la) + __uint_as_float(lb);
        }
        // epilogue: y[b*T + t][h*64 + d]; l gathered per output row via shfl
        const int bb2 = bh >> 4, h = bh & 15;
        #pragma unroll
        for (int r = 0; r < 16; ++r) {
            const int cr = (r & 3) + 8 * (r >> 2) + 4 * hi32;
            float inv = 1.0f / __shfl(lsum, cr);
            int t = q0w + cr;
            size_t off = ((size_t)(bb2 * T_DIM + t)) * 1024 + h * HDIM + q32;
            yb[off]      = f2bf(o0[r] * inv);
            yb[off + 32] = f2bf(o1[r] * inv);
        }
    }
}

extern "C" void kernel_launch(void* const* d_in, const int* in_sizes, int n_in,
                              void* d_out, int out_size, void* d_ws, size_t ws_size,
                              hipStream_t stream) {
    const float* x      = (const float*)d_in[0];   // [4,2048,1024]
    const float* w_attn = (const float*)d_in[1];   // [1024,3072]
    const float* w_proj = (const float*)d_in[2];   // [1024,1024]
    float* out = (float*)d_out;                    // [4,2048,1024]

    unsigned short* xb  = (unsigned short*)d_ws;           // [8192][1024]
    unsigned short* wat = xb  + (size_t)8192 * 1024;       // [3072][1024]
    unsigned short* wpt = wat + (size_t)3072 * 1024;       // [1024][1024]
    unsigned short* qb  = wpt + (size_t)1024 * 1024;       // [64][2048][64] natural
    unsigned short* kcm = qb  + (size_t)64 * 2048 * 64;    // [64][32][512][8] chunk-major
    unsigned short* vcm = kcm + (size_t)64 * 2048 * 64;    // [64][32][512][8] chunk-major-T
    unsigned short* yb  = vcm + (size_t)64 * 2048 * 64;    // [8192][1024]

    (void)hipFuncSetAttribute((const void*)gemm_bt_k<0>,
                              hipFuncAttributeMaxDynamicSharedMemorySize, 147456);
    (void)hipFuncSetAttribute((const void*)gemm_bt_k<1>,
                              hipFuncAttributeMaxDynamicSharedMemorySize, 147456);

    cvt_bf16_k<<<8192, 256, 0, stream>>>(x, xb, 8192 * 1024);
    transpose_wb_k<<<dim3(96, 32), 256, 0, stream>>>(w_attn, wat, 1024, 3072);
    transpose_wb_k<<<dim3(32, 32), 256, 0, stream>>>(w_proj, wpt, 1024, 1024);

    gemm_bt_k<0><<<dim3(24, 32), 512, 147456, stream>>>(xb, wat, qb, kcm, vcm, 8192, 3072, 1024);
    attn_k<<<dim3(4, 64), 512, 0, stream>>>(qb, kcm, vcm, yb);
    gemm_bt_k<1><<<dim3(8, 32), 512, 147456, stream>>>(yb, wpt, out, nullptr, nullptr, 8192, 1024, 1024);
}

// Round 9
// 168.895 us; speedup vs baseline: 1.3903x; 1.0216x over previous
//
#include <hip/hip_runtime.h>
#include <hip/hip_bf16.h>

// B=4, T=2048, C=1024, H=16, D=64. f32 in/out; bf16 MFMA internally.

typedef __attribute__((ext_vector_type(8))) short bf16x8;
typedef __attribute__((ext_vector_type(4))) float f32x4;
typedef __attribute__((ext_vector_type(16))) float f32x16;

#define T_DIM 2048
#define NHEAD 16
#define HDIM  64

__device__ __forceinline__ unsigned short f2bf(float f) {
    union { float f; unsigned int u; } v; v.f = f;
    unsigned int r = v.u + 0x7fffu + ((v.u >> 16) & 1u);   // RNE
    return (unsigned short)(r >> 16);
}

__device__ __forceinline__ unsigned cvtpk_bf16(float lo, float hi) {
    unsigned r;
    asm("v_cvt_pk_bf16_f32 %0, %1, %2" : "=v"(r) : "v"(lo), "v"(hi));
    return r;
}
__device__ __forceinline__ void pl32swap(unsigned &x, unsigned &y) {
    asm("v_permlane32_swap_b32 %0, %1" : "+v"(x), "+v"(y));
}
__device__ __forceinline__ bf16x8 mk8(unsigned w0, unsigned w1, unsigned w2, unsigned w3) {
    union { unsigned u[4]; bf16x8 v; } p;
    p.u[0] = w0; p.u[1] = w1; p.u[2] = w2; p.u[3] = w3;
    return p.v;
}

__device__ __forceinline__ void gload_lds16(const void* g, void* l) {
    __builtin_amdgcn_global_load_lds(
        (const __attribute__((address_space(1))) void*)g,
        (__attribute__((address_space(3))) void*)l,
        16, 0, 0);
}

// ---------------- f32 -> bf16 convert (vectorized) ----------------
__global__ void cvt_bf16_k(const float* __restrict__ src, unsigned short* __restrict__ dst, int n) {
    int i = (blockIdx.x * blockDim.x + threadIdx.x) * 4;
    if (i < n) {
        float4 v = *(const float4*)(src + i);
        ushort4 o; o.x = f2bf(v.x); o.y = f2bf(v.y); o.z = f2bf(v.z); o.w = f2bf(v.w);
        *(ushort4*)(dst + i) = o;
    }
}

// ---------------- transpose f32 [R][Cc] -> bf16 [Cc][R] ----------------
__global__ void transpose_wb_k(const float* __restrict__ src, unsigned short* __restrict__ dst,
                               int R, int Cc) {
    __shared__ float tile[32][33];
    int c0 = blockIdx.x * 32, r0 = blockIdx.y * 32;
    int tx = threadIdx.x & 31, ty = threadIdx.x >> 5;   // 32 x 8
    #pragma unroll
    for (int i = 0; i < 32; i += 8)
        tile[ty + i][tx] = src[(size_t)(r0 + ty + i) * Cc + c0 + tx];
    __syncthreads();
    #pragma unroll
    for (int i = 0; i < 32; i += 8)
        dst[(size_t)(c0 + ty + i) * R + r0 + tx] = f2bf(tile[tx][ty + i]);
}

// ---------------- 256x128 ring-3 counted-vmcnt GEMM, C = A[M,K] * Bt[N,K]^T ----------------
// 8 waves (4M x 2N). BK=64. LDS: 3 slots x (A 32K + B 16K) = 144 KiB.
// EPI==0: Q direct scatter (exp2-domain scale); K/V via LDS-staged chunk-major
// coalesced writes (reuses ring LDS after the K-loop). EPI==1: f32 [M,N].
template<int EPI>
__global__ __launch_bounds__(512, 2) void gemm_bt_k(
    const unsigned short* __restrict__ A, const unsigned short* __restrict__ Bt,
    void* __restrict__ out0, void* __restrict__ out1, void* __restrict__ out2,
    int M, int N, int K)
{
    extern __shared__ __align__(16) unsigned short smem[];
    unsigned short* sA = smem;           // [3][256][8ch][8] = 49152 shorts (96 KiB)
    unsigned short* sB = smem + 49152;   // [3][128][8ch][8] = 24576 shorts (48 KiB)

    const int tid = threadIdx.x, lane = tid & 63, wave = tid >> 6;
    const int wm = wave >> 1, wn = wave & 1;     // 4M x 2N
    const int lrow = lane & 15, hi = lane >> 4;

    const int nwg = gridDim.x * gridDim.y;
    const int lin = blockIdx.y * gridDim.x + blockIdx.x;
    const int lin2 = (lin & 7) * (nwg >> 3) + (lin >> 3);
    const int bxg = lin2 % gridDim.x, byg = lin2 / gridDim.x;
    const int row0 = byg * 256, col0 = bxg * 128;

    const int arow = tid >> 3;
    const int gk = ((tid & 7) ^ (arow & 7)) * 8;
    const unsigned short* gA0 = A + (size_t)(row0 + arow) * K + gk;
    const unsigned short* gA1 = A + (size_t)(row0 + arow + 64) * K + gk;
    const unsigned short* gA2 = A + (size_t)(row0 + arow + 128) * K + gk;
    const unsigned short* gA3 = A + (size_t)(row0 + arow + 192) * K + gk;
    const unsigned short* gB0 = Bt + (size_t)(col0 + arow) * K + gk;
    const unsigned short* gB1 = Bt + (size_t)(col0 + arow + 64) * K + gk;

    const int NT = K >> 6;

#define STAGE(ts, sl) { const size_t ko_ = (size_t)(ts) * 64; \
        unsigned short* dA_ = sA + (sl) * 16384; \
        unsigned short* dB_ = sB + (sl) * 8192; \
        gload_lds16(gA0 + ko_, dA_ + tid * 8); \
        gload_lds16(gA1 + ko_, dA_ + (tid + 512) * 8); \
        gload_lds16(gA2 + ko_, dA_ + (tid + 1024) * 8); \
        gload_lds16(gA3 + ko_, dA_ + (tid + 1536) * 8); \
        gload_lds16(gB0 + ko_, dB_ + tid * 8); \
        gload_lds16(gB1 + ko_, dB_ + (tid + 512) * 8); }

    f32x4 acc[4][4] = {};

    STAGE(0, 0);
    STAGE(1, 1);
    asm volatile("s_waitcnt vmcnt(6)" ::: "memory");
    __builtin_amdgcn_s_barrier();
    __builtin_amdgcn_sched_barrier(0);

    int slot = 0;
    for (int t = 0; t < NT; ++t) {
        if (t + 2 < NT) {
            const int s2 = (slot + 2 >= 3) ? slot - 1 : slot + 2;
            STAGE(t + 2, s2);
        }
        const unsigned short* As = sA + slot * 16384;
        const unsigned short* Bs = sB + slot * 8192;
        bf16x8 af[2][4], bf_[2][4];
        #pragma unroll
        for (int ks = 0; ks < 2; ++ks) {
            const int kc = (ks * 4 + hi) ^ (lrow & 7);
            #pragma unroll
            for (int mi = 0; mi < 4; ++mi)
                af[ks][mi] = *(const bf16x8*)&As[((wm * 64 + mi * 16 + lrow) * 8 + kc) * 8];
            #pragma unroll
            for (int ni = 0; ni < 4; ++ni)
                bf_[ks][ni] = *(const bf16x8*)&Bs[((wn * 64 + ni * 16 + lrow) * 8 + kc) * 8];
        }
        __builtin_amdgcn_s_setprio(1);
        #pragma unroll
        for (int ks = 0; ks < 2; ++ks)
            #pragma unroll
            for (int mi = 0; mi < 4; ++mi)
                #pragma unroll
                for (int ni = 0; ni < 4; ++ni)
                    acc[mi][ni] = __builtin_amdgcn_mfma_f32_16x16x32_bf16(af[ks][mi], bf_[ks][ni], acc[mi][ni], 0, 0, 0);
        __builtin_amdgcn_s_setprio(0);
        if (t + 2 < NT) { asm volatile("s_waitcnt vmcnt(6)" ::: "memory"); }
        else           { asm volatile("s_waitcnt vmcnt(0)" ::: "memory"); }
        __builtin_amdgcn_s_barrier();
        __builtin_amdgcn_sched_barrier(0);
        slot = (slot + 1 >= 3) ? 0 : slot + 1;
    }
#undef STAGE

    // epilogue: C/D layout row=hi*4+reg, col=lrow (verified m89)
    if (EPI == 1) {
        #pragma unroll
        for (int mi = 0; mi < 4; ++mi)
            #pragma unroll
            for (int ni = 0; ni < 4; ++ni) {
                int gm0 = row0 + wm * 64 + mi * 16 + hi * 4;
                int gn  = col0 + wn * 64 + ni * 16 + lrow;
                #pragma unroll
                for (int r = 0; r < 4; ++r)
                    ((float*)out0)[(size_t)(gm0 + r) * N + gn] = acc[mi][ni][r];
            }
    } else if (col0 < 1024) {
        // Q: natural [bh][t][d], exp2-domain scale; 32B-run scatter (R7-proven)
        const int bb = row0 >> 11;
        #pragma unroll
        for (int mi = 0; mi < 4; ++mi)
            #pragma unroll
            for (int ni = 0; ni < 4; ++ni) {
                int gm0 = row0 + wm * 64 + mi * 16 + hi * 4;
                int gn  = col0 + wn * 64 + ni * 16 + lrow;
                int h = (gn >> 6) & 15, d = gn & 63;
                #pragma unroll
                for (int r = 0; r < 4; ++r) {
                    int t = (gm0 + r) & 2047;
                    ((unsigned short*)out0)[((size_t)(bb * NHEAD + h) * T_DIM + t) * HDIM + d] =
                        f2bf(acc[mi][ni][r] * 0.18033688011112042f);
                }
            }
    } else {
        // K/V: LDS-staged chunk-major -> fully coalesced global writes.
        // local region: 2 heads x 4 t-chunks x 4096 shorts = 32768 shorts (64 KiB)
        const bool isK = (col0 < 2048);
        unsigned short* st = smem;
        __syncthreads();   // ring LDS dead; safe to reuse
        #pragma unroll
        for (int mi = 0; mi < 4; ++mi) {
            #pragma unroll
            for (int ni = 0; ni < 4; ++ni) {
                const int gnl = wn * 64 + ni * 16 + lrow;   // 0..127 within block
                const int hl = gnl >> 6, d = gnl & 63;
                #pragma unroll
                for (int r = 0; r < 4; ++r) {
                    const int tl = wm * 64 + mi * 16 + hi * 4 + r;   // 0..255
                    int idx;
                    if (isK) idx = (hl * 4 + (tl >> 6)) * 4096 + ((d >> 3) * 64 + (tl & 63)) * 8 + (d & 7);
                    else     idx = (hl * 4 + (tl >> 6)) * 4096 + (((tl >> 3) & 7) * 64 + d) * 8 + (tl & 7);
                    st[idx] = f2bf(acc[mi][ni][r]);
                }
            }
        }
        __syncthreads();
        unsigned short* outb = (unsigned short*)(isK ? out1 : out2);
        const int bb = row0 >> 11;
        const int h0 = (col0 & 1023) >> 6;
        const int tc0 = (row0 & 2047) >> 6;
        #pragma unroll
        for (int seg = 0; seg < 8; ++seg) {
            const int hl = seg >> 2, tc = seg & 3;
            const size_t gbase = ((size_t)(bb * NHEAD + h0 + hl) * 32 + tc0 + tc) * 4096;
            *(uint4*)(outb + gbase + tid * 8) = *(const uint4*)(st + seg * 4096 + tid * 8);
        }
    }
}

// ---------------- causal flash attention: 8 waves x 32 q-rows, swapped 32x32 QK^T ----------------
// grid (4, 64); block does q-tiles (bx, 7-bx) of 256 rows each -> uniform 36 kv-tiles.
// S^T = mfma_32x32x16(K, Q): lane holds col q=lane&31, rows kv=(r&3)+8*(r>>2)+4*(lane>>5).
// P = exp2(S-16) in regs; cvt_pk + permlane32_swap builds PV A-frags; no P LDS.
// K/V staged from chunk-major globals; all LDS reads contiguous per 32-lane half.
__global__ __launch_bounds__(512) void attn_k(
    const unsigned short* __restrict__ qb, const unsigned short* __restrict__ kcm,
    const unsigned short* __restrict__ vcm, unsigned short* __restrict__ yb)
{
    __shared__ __align__(16) unsigned short Ks[2][4096];
    __shared__ __align__(16) unsigned short Vs[2][4096];

    const int tid = threadIdx.x, lane = tid & 63, wave = tid >> 6;
    const int bh = blockIdx.y;
    const int q32 = lane & 31, hi32 = lane >> 5;
    const unsigned short* Kg = kcm + (size_t)bh * 32 * 4096;
    const unsigned short* Vg = vcm + (size_t)bh * 32 * 4096;

    #pragma unroll
    for (int pass = 0; pass < 2; ++pass) {
        const int bxx = (pass == 0) ? (int)blockIdx.x : (7 - (int)blockIdx.x);
        const int ntiles = 4 * bxx + 4;
        const int q0w = bxx * 256 + wave * 32;
        const int qg = q0w + q32;

        // Q B-fragments direct from global (pre-scaled into exp2 domain)
        const unsigned short* qrow = qb + ((size_t)bh * T_DIM + q0w + q32) * HDIM;
        bf16x8 qf[4];
        #pragma unroll
        for (int kc = 0; kc < 4; ++kc)
            qf[kc] = *(const bf16x8*)(qrow + kc * 16 + hi32 * 8);

        f32x16 o0 = {}, o1 = {};
        float lsum = 0.f;

        gload_lds16(Kg + tid * 8, &Ks[0][tid * 8]);
        gload_lds16(Vg + tid * 8, &Vs[0][tid * 8]);
        __syncthreads();

        int cur = 0;
        for (int jt = 0; jt < ntiles; ++jt) {
            if (jt + 1 < ntiles) {
                gload_lds16(Kg + (size_t)(jt + 1) * 4096 + tid * 8, &Ks[cur ^ 1][tid * 8]);
                gload_lds16(Vg + (size_t)(jt + 1) * 4096 + tid * 8, &Vs[cur ^ 1][tid * 8]);
            }
            if (jt * 64 <= q0w + 31) {   // wave-uniform skip of fully-masked tiles
                // S^T = K · Q  (exp2 domain)
                f32x16 s0 = {}, s1 = {};
                #pragma unroll
                for (int kc = 0; kc < 4; ++kc) {
                    bf16x8 a0 = *(const bf16x8*)&Ks[cur][((kc * 2 + hi32) * 64 + q32) * 8];
                    bf16x8 a1 = *(const bf16x8*)&Ks[cur][((kc * 2 + hi32) * 64 + 32 + q32) * 8];
                    s0 = __builtin_amdgcn_mfma_f32_32x32x16_bf16(a0, qf[kc], s0, 0, 0, 0);
                    s1 = __builtin_amdgcn_mfma_f32_32x32x16_bf16(a1, qf[kc], s1, 0, 0, 0);
                }
                // causal mask (diagonal tiles only); kv = jt*64 + blk*32 + crow(r)
                if (jt * 64 + 63 > q0w) {
                    #pragma unroll
                    for (int r = 0; r < 16; ++r) {
                        int kv0 = jt * 64 + (r & 3) + 8 * (r >> 2) + 4 * hi32;
                        if (kv0 > qg)      s0[r] = -1e30f;
                        if (kv0 + 32 > qg) s1[r] = -1e30f;
                    }
                }
                // P = exp2(S-16); pack to bf16; permlane-assemble PV A-frags
                bf16x8 pa[4];
                #pragma unroll
                for (int blk = 0; blk < 2; ++blk) {
                    float p_[16]; unsigned w_[8];
                    #pragma unroll
                    for (int i = 0; i < 16; ++i) {
                        float sv = blk ? s1[i] : s0[i];
                        p_[i] = __builtin_amdgcn_exp2f(sv - 16.0f);
                        lsum += p_[i];
                    }
                    #pragma unroll
                    for (int i = 0; i < 8; ++i) w_[i] = cvtpk_bf16(p_[2 * i], p_[2 * i + 1]);
                    pl32swap(w_[0], w_[2]); pl32swap(w_[1], w_[3]);
                    pl32swap(w_[4], w_[6]); pl32swap(w_[5], w_[7]);
                    pa[blk * 2]     = mk8(w_[0], w_[1], w_[2], w_[3]);
                    pa[blk * 2 + 1] = mk8(w_[4], w_[5], w_[6], w_[7]);
                }
                // O += P V
                #pragma unroll
                for (int kvc = 0; kvc < 4; ++kvc) {
                    bf16x8 b0 = *(const bf16x8*)&Vs[cur][((kvc * 2 + hi32) * 64 + q32) * 8];
                    bf16x8 b1 = *(const bf16x8*)&Vs[cur][((kvc * 2 + hi32) * 64 + 32 + q32) * 8];
                    o0 = __builtin_amdgcn_mfma_f32_32x32x16_bf16(pa[kvc], b0, o0, 0, 0, 0);
                    o1 = __builtin_amdgcn_mfma_f32_32x32x16_bf16(pa[kvc], b1, o1, 0, 0, 0);
                }
            }
            __syncthreads();   // drains prefetch; next tile ready
            cur ^= 1;
        }

        // l: own-half sum + partner-half via permlane pair
        {
            unsigned la = __float_as_uint(lsum), lb = __float_as_uint(lsum);
            pl32swap(la, lb);
            lsum = __uint_as_float(la) + __uint_as_float(lb);
        }
        // epilogue: y[b*T + t][h*64 + d]; l gathered per output row via shfl
        const int bb2 = bh >> 4, h = bh & 15;
        #pragma unroll
        for (int r = 0; r < 16; ++r) {
            const int cr = (r & 3) + 8 * (r >> 2) + 4 * hi32;
            float inv = 1.0f / __shfl(lsum, cr);
            int t = q0w + cr;
            size_t off = ((size_t)(bb2 * T_DIM + t)) * 1024 + h * HDIM + q32;
            yb[off]      = f2bf(o0[r] * inv);
            yb[off + 32] = f2bf(o1[r] * inv);
        }
    }
}

extern "C" void kernel_launch(void* const* d_in, const int* in_sizes, int n_in,
                              void* d_out, int out_size, void* d_ws, size_t ws_size,
                              hipStream_t stream) {
    const float* x      = (const float*)d_in[0];   // [4,2048,1024]
    const float* w_attn = (const float*)d_in[1];   // [1024,3072]
    const float* w_proj = (const float*)d_in[2];   // [1024,1024]
    float* out = (float*)d_out;                    // [4,2048,1024]

    unsigned short* xb  = (unsigned short*)d_ws;           // [8192][1024]
    unsigned short* wat = xb  + (size_t)8192 * 1024;       // [3072][1024]
    unsigned short* wpt = wat + (size_t)3072 * 1024;       // [1024][1024]
    unsigned short* qb  = wpt + (size_t)1024 * 1024;       // [64][2048][64] natural
    unsigned short* kcm = qb  + (size_t)64 * 2048 * 64;    // [64][32][512][8] chunk-major
    unsigned short* vcm = kcm + (size_t)64 * 2048 * 64;    // [64][32][512][8] chunk-major-T
    unsigned short* yb  = vcm + (size_t)64 * 2048 * 64;    // [8192][1024]

    (void)hipFuncSetAttribute((const void*)gemm_bt_k<0>,
                              hipFuncAttributeMaxDynamicSharedMemorySize, 147456);
    (void)hipFuncSetAttribute((const void*)gemm_bt_k<1>,
                              hipFuncAttributeMaxDynamicSharedMemorySize, 147456);

    cvt_bf16_k<<<8192, 256, 0, stream>>>(x, xb, 8192 * 1024);
    transpose_wb_k<<<dim3(96, 32), 256, 0, stream>>>(w_attn, wat, 1024, 3072);
    transpose_wb_k<<<dim3(32, 32), 256, 0, stream>>>(w_proj, wpt, 1024, 1024);

    gemm_bt_k<0><<<dim3(24, 32), 512, 147456, stream>>>(xb, wat, qb, kcm, vcm, 8192, 3072, 1024);
    attn_k<<<dim3(4, 64), 512, 0, stream>>>(qb, kcm, vcm, yb);
    gemm_bt_k<1><<<dim3(8, 32), 512, 147456, stream>>>(yb, wpt, out, nullptr, nullptr, 8192, 1024, 1024);
}

// Round 10
// 167.479 us; speedup vs baseline: 1.4021x; 1.0085x over previous
//
#include <hip/hip_runtime.h>
#include <hip/hip_bf16.h>

// B=4, T=2048, C=1024, H=16, D=64. f32 in/out; bf16 MFMA internally.

typedef __attribute__((ext_vector_type(8))) short bf16x8;
typedef __attribute__((ext_vector_type(4))) float f32x4;
typedef __attribute__((ext_vector_type(16))) float f32x16;

#define T_DIM 2048
#define NHEAD 16
#define HDIM  64

__device__ __forceinline__ unsigned short f2bf(float f) {
    union { float f; unsigned int u; } v; v.f = f;
    unsigned int r = v.u + 0x7fffu + ((v.u >> 16) & 1u);   // RNE
    return (unsigned short)(r >> 16);
}

__device__ __forceinline__ unsigned cvtpk_bf16(float lo, float hi) {
    unsigned r;
    asm("v_cvt_pk_bf16_f32 %0, %1, %2" : "=v"(r) : "v"(lo), "v"(hi));
    return r;
}
__device__ __forceinline__ void pl32swap(unsigned &x, unsigned &y) {
    asm("v_permlane32_swap_b32 %0, %1" : "+v"(x), "+v"(y));
}
__device__ __forceinline__ bf16x8 mk8(unsigned w0, unsigned w1, unsigned w2, unsigned w3) {
    union { unsigned u[4]; bf16x8 v; } p;
    p.u[0] = w0; p.u[1] = w1; p.u[2] = w2; p.u[3] = w3;
    return p.v;
}

__device__ __forceinline__ void gload_lds16(const void* g, void* l) {
    __builtin_amdgcn_global_load_lds(
        (const __attribute__((address_space(1))) void*)g,
        (__attribute__((address_space(3))) void*)l,
        16, 0, 0);
}

// ---------------- f32 -> bf16 convert (vectorized) ----------------
__global__ void cvt_bf16_k(const float* __restrict__ src, unsigned short* __restrict__ dst, int n) {
    int i = (blockIdx.x * blockDim.x + threadIdx.x) * 4;
    if (i < n) {
        float4 v = *(const float4*)(src + i);
        ushort4 o; o.x = f2bf(v.x); o.y = f2bf(v.y); o.z = f2bf(v.z); o.w = f2bf(v.w);
        *(ushort4*)(dst + i) = o;
    }
}

// ---------------- transpose f32 [R][Cc] -> bf16 [Cc][R] ----------------
__global__ void transpose_wb_k(const float* __restrict__ src, unsigned short* __restrict__ dst,
                               int R, int Cc) {
    __shared__ float tile[32][33];
    int c0 = blockIdx.x * 32, r0 = blockIdx.y * 32;
    int tx = threadIdx.x & 31, ty = threadIdx.x >> 5;   // 32 x 8
    #pragma unroll
    for (int i = 0; i < 32; i += 8)
        tile[ty + i][tx] = src[(size_t)(r0 + ty + i) * Cc + c0 + tx];
    __syncthreads();
    #pragma unroll
    for (int i = 0; i < 32; i += 8)
        dst[(size_t)(c0 + ty + i) * R + r0 + tx] = f2bf(tile[tx][ty + i]);
}

// ---------------- 256x128 ring-3 phase-split GEMM, C = A[M,K] * Bt[N,K]^T ----------------
// 8 waves (4M x 2N). BK=64. LDS: 3 slots x (A 32K + B 16K) = 144 KiB.
// Per K-tile, 2 phases: {8 ds_read(ks) + 3 stage loads -> s_barrier -> lgkmcnt(0) ->
// setprio(1) 16 MFMA setprio(0) -> s_barrier}; vmcnt(6) once per tile (counted, never drain).
// EPI==0: Q direct scatter; K/V via LDS-staged chunk-major coalesced writes. EPI==1: f32 [M,N].
template<int EPI>
__global__ __launch_bounds__(512, 2) void gemm_bt_k(
    const unsigned short* __restrict__ A, const unsigned short* __restrict__ Bt,
    void* __restrict__ out0, void* __restrict__ out1, void* __restrict__ out2,
    int M, int N, int K)
{
    extern __shared__ __align__(16) unsigned short smem[];
    unsigned short* sA = smem;           // [3][256][8ch][8] = 49152 shorts (96 KiB)
    unsigned short* sB = smem + 49152;   // [3][128][8ch][8] = 24576 shorts (48 KiB)

    const int tid = threadIdx.x, lane = tid & 63, wave = tid >> 6;
    const int wm = wave >> 1, wn = wave & 1;     // 4M x 2N
    const int lrow = lane & 15, hi = lane >> 4;

    const int nwg = gridDim.x * gridDim.y;
    const int lin = blockIdx.y * gridDim.x + blockIdx.x;
    const int lin2 = (lin & 7) * (nwg >> 3) + (lin >> 3);
    const int bxg = lin2 % gridDim.x, byg = lin2 / gridDim.x;
    const int row0 = byg * 256, col0 = bxg * 128;

    const int arow = tid >> 3;
    const int gk = ((tid & 7) ^ (arow & 7)) * 8;
    const unsigned short* gA0 = A + (size_t)(row0 + arow) * K + gk;
    const unsigned short* gA1 = A + (size_t)(row0 + arow + 64) * K + gk;
    const unsigned short* gA2 = A + (size_t)(row0 + arow + 128) * K + gk;
    const unsigned short* gA3 = A + (size_t)(row0 + arow + 192) * K + gk;
    const unsigned short* gB0 = Bt + (size_t)(col0 + arow) * K + gk;
    const unsigned short* gB1 = Bt + (size_t)(col0 + arow + 64) * K + gk;

    const int NT = K >> 6;

#define STAGE_P0(ts, sl) { const size_t ko_ = (size_t)(ts) * 64; \
        unsigned short* dA_ = sA + (sl) * 16384; \
        gload_lds16(gA0 + ko_, dA_ + tid * 8); \
        gload_lds16(gA1 + ko_, dA_ + (tid + 512) * 8); \
        gload_lds16(gA2 + ko_, dA_ + (tid + 1024) * 8); }
#define STAGE_P1(ts, sl) { const size_t ko_ = (size_t)(ts) * 64; \
        unsigned short* dA_ = sA + (sl) * 16384; \
        unsigned short* dB_ = sB + (sl) * 8192; \
        gload_lds16(gA3 + ko_, dA_ + (tid + 1536) * 8); \
        gload_lds16(gB0 + ko_, dB_ + tid * 8); \
        gload_lds16(gB1 + ko_, dB_ + (tid + 512) * 8); }

    f32x4 acc[4][4] = {};

    // prologue: stage tiles 0,1; counted wait for tile 0
    STAGE_P0(0, 0); STAGE_P1(0, 0);
    STAGE_P0(1, 1); STAGE_P1(1, 1);
    asm volatile("s_waitcnt vmcnt(6)" ::: "memory");
    __builtin_amdgcn_s_barrier();
    __builtin_amdgcn_sched_barrier(0);

    int slot = 0;
    for (int t = 0; t < NT; ++t) {
        const int s2 = (slot + 2 >= 3) ? slot - 1 : slot + 2;
        const unsigned short* As = sA + slot * 16384;
        const unsigned short* Bs = sB + slot * 8192;
        bf16x8 af[4], bf_[4];

        // ---------------- phase 0: ks = 0 ----------------
        {
            const int kc = hi ^ (lrow & 7);
            #pragma unroll
            for (int mi = 0; mi < 4; ++mi)
                af[mi] = *(const bf16x8*)&As[((wm * 64 + mi * 16 + lrow) * 8 + kc) * 8];
            #pragma unroll
            for (int ni = 0; ni < 4; ++ni)
                bf_[ni] = *(const bf16x8*)&Bs[((wn * 64 + ni * 16 + lrow) * 8 + kc) * 8];
        }
        if (t + 2 < NT) STAGE_P0(t + 2, s2);
        __builtin_amdgcn_s_barrier();
        asm volatile("s_waitcnt lgkmcnt(0)" ::: "memory");
        __builtin_amdgcn_sched_barrier(0);
        __builtin_amdgcn_s_setprio(1);
        #pragma unroll
        for (int mi = 0; mi < 4; ++mi)
            #pragma unroll
            for (int ni = 0; ni < 4; ++ni)
                acc[mi][ni] = __builtin_amdgcn_mfma_f32_16x16x32_bf16(af[mi], bf_[ni], acc[mi][ni], 0, 0, 0);
        __builtin_amdgcn_s_setprio(0);
        __builtin_amdgcn_s_barrier();

        // ---------------- phase 1: ks = 1 ----------------
        {
            const int kc = (4 + hi) ^ (lrow & 7);
            #pragma unroll
            for (int mi = 0; mi < 4; ++mi)
                af[mi] = *(const bf16x8*)&As[((wm * 64 + mi * 16 + lrow) * 8 + kc) * 8];
            #pragma unroll
            for (int ni = 0; ni < 4; ++ni)
                bf_[ni] = *(const bf16x8*)&Bs[((wn * 64 + ni * 16 + lrow) * 8 + kc) * 8];
        }
        if (t + 2 < NT) STAGE_P1(t + 2, s2);
        __builtin_amdgcn_s_barrier();
        asm volatile("s_waitcnt lgkmcnt(0)" ::: "memory");
        __builtin_amdgcn_sched_barrier(0);
        __builtin_amdgcn_s_setprio(1);
        #pragma unroll
        for (int mi = 0; mi < 4; ++mi)
            #pragma unroll
            for (int ni = 0; ni < 4; ++ni)
                acc[mi][ni] = __builtin_amdgcn_mfma_f32_16x16x32_bf16(af[mi], bf_[ni], acc[mi][ni], 0, 0, 0);
        __builtin_amdgcn_s_setprio(0);
        // counted K-tile boundary: tile t+1 resident; only t+2's 6 loads in flight
        if (t + 2 < NT) { asm volatile("s_waitcnt vmcnt(6)" ::: "memory"); }
        else           { asm volatile("s_waitcnt vmcnt(0)" ::: "memory"); }
        __builtin_amdgcn_s_barrier();
        __builtin_amdgcn_sched_barrier(0);
        slot = (slot + 1 >= 3) ? 0 : slot + 1;
    }
#undef STAGE_P0
#undef STAGE_P1

    // epilogue: C/D layout row=hi*4+reg, col=lrow (verified m89)
    if (EPI == 1) {
        #pragma unroll
        for (int mi = 0; mi < 4; ++mi)
            #pragma unroll
            for (int ni = 0; ni < 4; ++ni) {
                int gm0 = row0 + wm * 64 + mi * 16 + hi * 4;
                int gn  = col0 + wn * 64 + ni * 16 + lrow;
                #pragma unroll
                for (int r = 0; r < 4; ++r)
                    ((float*)out0)[(size_t)(gm0 + r) * N + gn] = acc[mi][ni][r];
            }
    } else if (col0 < 1024) {
        // Q: natural [bh][t][d], exp2-domain scale; 32B-run scatter
        const int bb = row0 >> 11;
        #pragma unroll
        for (int mi = 0; mi < 4; ++mi)
            #pragma unroll
            for (int ni = 0; ni < 4; ++ni) {
                int gm0 = row0 + wm * 64 + mi * 16 + hi * 4;
                int gn  = col0 + wn * 64 + ni * 16 + lrow;
                int h = (gn >> 6) & 15, d = gn & 63;
                #pragma unroll
                for (int r = 0; r < 4; ++r) {
                    int t = (gm0 + r) & 2047;
                    ((unsigned short*)out0)[((size_t)(bb * NHEAD + h) * T_DIM + t) * HDIM + d] =
                        f2bf(acc[mi][ni][r] * 0.18033688011112042f);
                }
            }
    } else {
        // K/V: LDS-staged chunk-major -> fully coalesced global writes.
        const bool isK = (col0 < 2048);
        unsigned short* st = smem;
        __syncthreads();   // ring LDS dead; safe to reuse
        #pragma unroll
        for (int mi = 0; mi < 4; ++mi) {
            #pragma unroll
            for (int ni = 0; ni < 4; ++ni) {
                const int gnl = wn * 64 + ni * 16 + lrow;   // 0..127 within block
                const int hl = gnl >> 6, d = gnl & 63;
                #pragma unroll
                for (int r = 0; r < 4; ++r) {
                    const int tl = wm * 64 + mi * 16 + hi * 4 + r;   // 0..255
                    int idx;
                    if (isK) idx = (hl * 4 + (tl >> 6)) * 4096 + ((d >> 3) * 64 + (tl & 63)) * 8 + (d & 7);
                    else     idx = (hl * 4 + (tl >> 6)) * 4096 + (((tl >> 3) & 7) * 64 + d) * 8 + (tl & 7);
                    st[idx] = f2bf(acc[mi][ni][r]);
                }
            }
        }
        __syncthreads();
        unsigned short* outb = (unsigned short*)(isK ? out1 : out2);
        const int bb = row0 >> 11;
        const int h0 = (col0 & 1023) >> 6;
        const int tc0 = (row0 & 2047) >> 6;
        #pragma unroll
        for (int seg = 0; seg < 8; ++seg) {
            const int hl = seg >> 2, tc = seg & 3;
            const size_t gbase = ((size_t)(bb * NHEAD + h0 + hl) * 32 + tc0 + tc) * 4096;
            *(uint4*)(outb + gbase + tid * 8) = *(const uint4*)(st + seg * 4096 + tid * 8);
        }
    }
}

// ---------------- causal flash attention: 8 waves x 32 q-rows, swapped 32x32 QK^T ----------------
// grid (4, 64); block does q-tiles (bx, 7-bx) of 256 rows each -> uniform 36 kv-tiles.
// S^T = mfma_32x32x16(K, Q): lane holds col q=lane&31, rows kv=(r&3)+8*(r>>2)+4*(lane>>5).
// P = exp2(S-16) in regs; cvt_pk + permlane32_swap builds PV A-frags; no P LDS.
__global__ __launch_bounds__(512) void attn_k(
    const unsigned short* __restrict__ qb, const unsigned short* __restrict__ kcm,
    const unsigned short* __restrict__ vcm, unsigned short* __restrict__ yb)
{
    __shared__ __align__(16) unsigned short Ks[2][4096];
    __shared__ __align__(16) unsigned short Vs[2][4096];

    const int tid = threadIdx.x, lane = tid & 63, wave = tid >> 6;
    const int bh = blockIdx.y;
    const int q32 = lane & 31, hi32 = lane >> 5;
    const unsigned short* Kg = kcm + (size_t)bh * 32 * 4096;
    const unsigned short* Vg = vcm + (size_t)bh * 32 * 4096;

    #pragma unroll
    for (int pass = 0; pass < 2; ++pass) {
        const int bxx = (pass == 0) ? (int)blockIdx.x : (7 - (int)blockIdx.x);
        const int ntiles = 4 * bxx + 4;
        const int q0w = bxx * 256 + wave * 32;
        const int qg = q0w + q32;

        // Q B-fragments direct from global (pre-scaled into exp2 domain)
        const unsigned short* qrow = qb + ((size_t)bh * T_DIM + q0w + q32) * HDIM;
        bf16x8 qf[4];
        #pragma unroll
        for (int kc = 0; kc < 4; ++kc)
            qf[kc] = *(const bf16x8*)(qrow + kc * 16 + hi32 * 8);

        f32x16 o0 = {}, o1 = {};
        float lsum = 0.f;

        gload_lds16(Kg + tid * 8, &Ks[0][tid * 8]);
        gload_lds16(Vg + tid * 8, &Vs[0][tid * 8]);
        __syncthreads();

        int cur = 0;
        for (int jt = 0; jt < ntiles; ++jt) {
            if (jt + 1 < ntiles) {
                gload_lds16(Kg + (size_t)(jt + 1) * 4096 + tid * 8, &Ks[cur ^ 1][tid * 8]);
                gload_lds16(Vg + (size_t)(jt + 1) * 4096 + tid * 8, &Vs[cur ^ 1][tid * 8]);
            }
            if (jt * 64 <= q0w + 31) {   // wave-uniform skip of fully-masked tiles
                // S^T = K · Q  (exp2 domain)
                f32x16 s0 = {}, s1 = {};
                #pragma unroll
                for (int kc = 0; kc < 4; ++kc) {
                    bf16x8 a0 = *(const bf16x8*)&Ks[cur][((kc * 2 + hi32) * 64 + q32) * 8];
                    bf16x8 a1 = *(const bf16x8*)&Ks[cur][((kc * 2 + hi32) * 64 + 32 + q32) * 8];
                    s0 = __builtin_amdgcn_mfma_f32_32x32x16_bf16(a0, qf[kc], s0, 0, 0, 0);
                    s1 = __builtin_amdgcn_mfma_f32_32x32x16_bf16(a1, qf[kc], s1, 0, 0, 0);
                }
                // causal mask (diagonal tiles only); kv = jt*64 + blk*32 + crow(r)
                if (jt * 64 + 63 > q0w) {
                    #pragma unroll
                    for (int r = 0; r < 16; ++r) {
                        int kv0 = jt * 64 + (r & 3) + 8 * (r >> 2) + 4 * hi32;
                        if (kv0 > qg)      s0[r] = -1e30f;
                        if (kv0 + 32 > qg) s1[r] = -1e30f;
                    }
                }
                // P = exp2(S-16); pack to bf16; permlane-assemble PV A-frags
                bf16x8 pa[4];
                #pragma unroll
                for (int blk = 0; blk < 2; ++blk) {
                    float p_[16]; unsigned w_[8];
                    #pragma unroll
                    for (int i = 0; i < 16; ++i) {
                        float sv = blk ? s1[i] : s0[i];
                        p_[i] = __builtin_amdgcn_exp2f(sv - 16.0f);
                        lsum += p_[i];
                    }
                    #pragma unroll
                    for (int i = 0; i < 8; ++i) w_[i] = cvtpk_bf16(p_[2 * i], p_[2 * i + 1]);
                    pl32swap(w_[0], w_[2]); pl32swap(w_[1], w_[3]);
                    pl32swap(w_[4], w_[6]); pl32swap(w_[5], w_[7]);
                    pa[blk * 2]     = mk8(w_[0], w_[1], w_[2], w_[3]);
                    pa[blk * 2 + 1] = mk8(w_[4], w_[5], w_[6], w_[7]);
                }
                // O += P V
                #pragma unroll
                for (int kvc = 0; kvc < 4; ++kvc) {
                    bf16x8 b0 = *(const bf16x8*)&Vs[cur][((kvc * 2 + hi32) * 64 + q32) * 8];
                    bf16x8 b1 = *(const bf16x8*)&Vs[cur][((kvc * 2 + hi32) * 64 + 32 + q32) * 8];
                    o0 = __builtin_amdgcn_mfma_f32_32x32x16_bf16(pa[kvc], b0, o0, 0, 0, 0);
                    o1 = __builtin_amdgcn_mfma_f32_32x32x16_bf16(pa[kvc], b1, o1, 0, 0, 0);
                }
            }
            __syncthreads();   // drains prefetch; next tile ready
            cur ^= 1;
        }

        // l: own-half sum + partner-half via permlane pair
        {
            unsigned la = __float_as_uint(lsum), lb = __float_as_uint(lsum);
            pl32swap(la, lb);
            lsum = __uint_as_float(la) + __uint_as_float(lb);
        }
        // epilogue: y[b*T + t][h*64 + d]; l gathered per output row via shfl
        const int bb2 = bh >> 4, h = bh & 15;
        #pragma unroll
        for (int r = 0; r < 16; ++r) {
            const int cr = (r & 3) + 8 * (r >> 2) + 4 * hi32;
            float inv = 1.0f / __shfl(lsum, cr);
            int t = q0w + cr;
            size_t off = ((size_t)(bb2 * T_DIM + t)) * 1024 + h * HDIM + q32;
            yb[off]      = f2bf(o0[r] * inv);
            yb[off + 32] = f2bf(o1[r] * inv);
        }
    }
}

extern "C" void kernel_launch(void* const* d_in, const int* in_sizes, int n_in,
                              void* d_out, int out_size, void* d_ws, size_t ws_size,
                              hipStream_t stream) {
    const float* x      = (const float*)d_in[0];   // [4,2048,1024]
    const float* w_attn = (const float*)d_in[1];   // [1024,3072]
    const float* w_proj = (const float*)d_in[2];   // [1024,1024]
    float* out = (float*)d_out;                    // [4,2048,1024]

    unsigned short* xb  = (unsigned short*)d_ws;           // [8192][1024]
    unsigned short* wat = xb  + (size_t)8192 * 1024;       // [3072][1024]
    unsigned short* wpt = wat + (size_t)3072 * 1024;       // [1024][1024]
    unsigned short* qb  = wpt + (size_t)1024 * 1024;       // [64][2048][64] natural
    unsigned short* kcm = qb  + (size_t)64 * 2048 * 64;    // [64][32][512][8] chunk-major
    unsigned short* vcm = kcm + (size_t)64 * 2048 * 64;    // [64][32][512][8] chunk-major-T
    unsigned short* yb  = vcm + (size_t)64 * 2048 * 64;    // [8192][1024]

    (void)hipFuncSetAttribute((const void*)gemm_bt_k<0>,
                              hipFuncAttributeMaxDynamicSharedMemorySize, 147456);
    (void)hipFuncSetAttribute((const void*)gemm_bt_k<1>,
                              hipFuncAttributeMaxDynamicSharedMemorySize, 147456);

    cvt_bf16_k<<<8192, 256, 0, stream>>>(x, xb, 8192 * 1024);
    transpose_wb_k<<<dim3(96, 32), 256, 0, stream>>>(w_attn, wat, 1024, 3072);
    transpose_wb_k<<<dim3(32, 32), 256, 0, stream>>>(w_proj, wpt, 1024, 1024);

    gemm_bt_k<0><<<dim3(24, 32), 512, 147456, stream>>>(xb, wat, qb, kcm, vcm, 8192, 3072, 1024);
    attn_k<<<dim3(4, 64), 512, 0, stream>>>(qb, kcm, vcm, yb);
    gemm_bt_k<1><<<dim3(8, 32), 512, 147456, stream>>>(yb, wpt, out, nullptr, nullptr, 8192, 1024, 1024);
}